// Round 12
// baseline (112.306 us; speedup 1.0000x reference)
//
#include <hip/hip_runtime.h>
#include <math.h>

namespace {
constexpr int KF = 1152;   // padded feature dim (1120 used + 32 zeros)
}

typedef __bf16 v8bf __attribute__((ext_vector_type(8)));
typedef float  v4f  __attribute__((ext_vector_type(4)));

__device__ __forceinline__ unsigned short f2bf(float f) {
    union { float f; unsigned u; } v; v.f = f;
    unsigned r = v.u + 0x7FFFu + ((v.u >> 16) & 1u);
    return (unsigned short)(r >> 16);
}

__device__ __forceinline__ v8bf as_v8bf(uint4 u) {
    union { uint4 u; v8bf b; } c; c.u = u; return c.b;
}

// ---------------------------------------------------------------------------
// K1: per-row feature builder, WAVE-PER-ROW, barrier-free.
// Evidence: k_feat block duration ~40-50us INVARIANT to work/block (RPB
// 2/4/8), traffic (k_rest: no w2), and occupancy >=4blk/CU -> fixed
// per-block latency floor from the 6-barrier serial stage chain (every
// stage: all waves wait for the slowest, memory pipe restarts cold).
// Fix: one wave owns one row end-to-end; the ONLY barrier is the one-time
// tri-table init. Stage deps are same-wave LDS (in-order DS pipe; compiler
// fences pin program order). 512 blocks x 4 waves = 2048 rows; waves fully
// independent -> latencies overlap across 8 waves/CU.
// Math per element identical to the verified R10 kernel (raw: b2 init +
// k=0..63 ascending; G: unrolled 8xfloat4; u: rowoff form). Only c's
// 32-term dot becomes a shuffle tree (<=ulp, feeds sqrt; absmax-safe).
// ---------------------------------------------------------------------------
__global__ __launch_bounds__(256) void k_feat(
    const float* __restrict__ Q, const float* __restrict__ K,
    const float* __restrict__ w1, const float* __restrict__ b1,
    const float* __restrict__ w2, const float* __restrict__ b2,
    unsigned short* __restrict__ featA, unsigned short* __restrict__ featB,
    float* __restrict__ cOut)
{
    __shared__ __attribute__((aligned(16))) float x_s[4][32];
    __shared__ __attribute__((aligned(16))) float h_s[4][64];
    __shared__ __attribute__((aligned(16))) float L_s[4][32][36];
    __shared__ __attribute__((aligned(16))) float G_s[4][528];   // packed lower tri
    __shared__ __attribute__((aligned(16))) float u_s[4][32];
    __shared__ unsigned short tri_s[528];                        // (i<<8)|j
    __shared__ unsigned short rowoff_s[32];                      // j*(65-j)/2

    const int t    = threadIdx.x;
    const int lane = t & 63;
    const int w    = t >> 6;                 // wave id = row slot
    const int g    = blockIdx.x * 4 + w;     // this wave's global row (0..2047)

    // ---- one-time tables; the ONLY barrier in the kernel
    for (int pr = t; pr < 528; pr += 256) {
        int j = (int)((65.0f - sqrtf(4225.0f - 8.0f * (float)pr)) * 0.5f);
        while (j > 0 && j * (65 - j) / 2 > pr) --j;
        while ((j + 1) * (64 - j) / 2 <= pr) ++j;
        int i = j + (pr - j * (65 - j) / 2);
        tri_s[pr] = (unsigned short)((i << 8) | j);
    }
    if (t < 32) rowoff_s[t] = (unsigned short)(t * (65 - t) / 2);
    __syncthreads();

    // ---- x load (lanes 0-31); value kept in register for c-stage
    const float* src = (g < 1024) ? (Q + (size_t)g * 32)
                                  : (K + (size_t)(g - 1024) * 32);
    float xi = 0.0f;
    if (lane < 32) { xi = src[lane]; x_s[w][lane] = xi; }
    asm volatile("" ::: "memory");   // pin order: x write < h reads (in-order DS pipe)

    // ---- h = silu(x @ w1 + b1): lane j computes h[j]
    {
        const int j = lane;
        float z = b1[j];
        #pragma unroll
        for (int i = 0; i < 32; ++i) z = fmaf(x_s[w][i], w1[i * 64 + j], z);
        h_s[w][j] = z / (1.0f + __expf(-z));
    }
    asm volatile("" ::: "memory");

    // ---- raw = h @ w2 + b2 -> L: lane owns 4 col-quads (passes p=0..3),
    // quad index p*64+lane -> consecutive lanes = consecutive 16B (coalesced).
    // Fully-upper quads (j0 > i) skip the FMA/load block (outputs are val=0).
    #pragma unroll
    for (int p = 0; p < 4; ++p) {
        const int p4 = (p * 64 + lane) * 4;
        const int i  = p4 >> 5;
        const int j0 = p4 & 31;
        float4 bq = *(const float4*)&b2[p4];
        float a0 = bq.x, a1 = bq.y, a2 = bq.z, a3 = bq.w;
        if (j0 <= i) {
            for (int jb = 0; jb < 8; ++jb) {
                float h8[8];
                *(float4*)&h8[0] = *(const float4*)&h_s[w][jb * 8 + 0];
                *(float4*)&h8[4] = *(const float4*)&h_s[w][jb * 8 + 4];
                #pragma unroll
                for (int jj = 0; jj < 8; ++jj) {
                    float4 wv4 = *(const float4*)&w2[(size_t)(jb * 8 + jj) * 1024 + p4];
                    a0 = fmaf(h8[jj], wv4.x, a0);
                    a1 = fmaf(h8[jj], wv4.y, a1);
                    a2 = fmaf(h8[jj], wv4.z, a2);
                    a3 = fmaf(h8[jj], wv4.w, a3);
                }
            }
        }
        float accq[4] = { a0, a1, a2, a3 };
        float4 lv;
        float* lvp = (float*)&lv;
        #pragma unroll
        for (int e = 0; e < 4; ++e) {
            int j = j0 + e;
            float raw = accq[e];
            float ex = __expf(0.4f * raw);
            float c5 = 5.0f * (ex - 1.0f) / (ex + 1.0f);   // 5*tanh(raw/5)
            float val;
            if (i < j)       val = 0.0f;
            else if (i == j) { float z = c5 + 1.0f; val = log1pf(__expf(z)) + 1e-4f; }
            else             val = c5;
            lvp[e] = val;
        }
        *(float4*)&L_s[w][i][j0] = lv;
    }
    asm volatile("" ::: "memory");

    // ---- G = L L^T: 528 outputs / 64 lanes, fixed-trip unrolled dot
    #pragma unroll
    for (int pp = 0; pp < 9; ++pp) {
        const int pr = pp * 64 + lane;
        if (pr < 528) {
            int tv = tri_s[pr];
            int i = tv >> 8, j = tv & 255;
            const float* Li = &L_s[w][i][0];
            const float* Lj = &L_s[w][j][0];
            float s = 0.0f;
            #pragma unroll
            for (int q = 0; q < 8; ++q) {
                float4 a  = *(const float4*)&Li[q * 4];
                float4 bb = *(const float4*)&Lj[q * 4];
                s += a.x * bb.x + a.y * bb.y + a.z * bb.z + a.w * bb.w;
            }
            G_s[w][pr] = s;
        }
    }
    asm volatile("" ::: "memory");

    // ---- u = G x (lanes 0-31)
    float uval = 0.0f;
    if (lane < 32) {
        const int i = lane;
        const int base_i = (int)rowoff_s[i] - i;
        #pragma unroll
        for (int j = 0; j < 32; ++j) {
            int gidx = (j <= i) ? ((int)rowoff_s[j] + i - j) : (base_i + j);
            uval = fmaf(G_s[w][gidx], x_s[w][j], uval);
        }
        u_s[w][i] = uval;
    }
    asm volatile("" ::: "memory");

    // ---- c = u . x : shuffle tree over lanes 0-31 (xi held in register)
    {
        float prod = (lane < 32) ? uval * xi : 0.0f;
        #pragma unroll
        for (int off = 16; off > 0; off >>= 1) prod += __shfl_down(prod, off);
        if (lane == 0) cOut[g] = prod;
    }

    // ---- feature write: 288 quads/row over 64 lanes (coalesced uint2)
    {
        const bool isA = (g < 1024);
        unsigned short* dst = isA ? (featA + (size_t)g * KF)
                                  : (featB + (size_t)(g - 1024) * KF);
        #pragma unroll
        for (int pp = 0; pp < 5; ++pp) {
            const int qidx = pp * 64 + lane;
            if (qidx < KF / 4) {
                const int pos = qidx * 4;
                unsigned short ev[4];
                #pragma unroll
                for (int e = 0; e < 4; ++e) {
                    int p = pos + e;
                    float va;
                    if (p < 1056) {
                        int pr = (p < 528) ? p : p - 528;
                        bool wantG = (p < 528) ? isA : !isA;
                        int tv = tri_s[pr];
                        int i = tv >> 8, j = tv & 255;
                        float gv = G_s[w][pr] * ((i == j) ? 1.0f : 2.0f);
                        float ov = x_s[w][i] * x_s[w][j];
                        va = wantG ? gv : ov;
                    } else if (p < 1088) {
                        int i = p - 1056;
                        va = isA ? u_s[w][i] : -2.0f * x_s[w][i];
                    } else if (p < 1120) {
                        int i = p - 1088;
                        va = isA ? x_s[w][i] : -2.0f * u_s[w][i];
                    } else {
                        va = 0.0f;   // ws re-poisoned 0xAA — pad must be written
                    }
                    ev[e] = f2bf(va);
                }
                uint2 wpk;
                wpk.x = (unsigned)ev[0] | ((unsigned)ev[1] << 16);
                wpk.y = (unsigned)ev[2] | ((unsigned)ev[3] << 16);
                *(uint2*)(dst + pos) = wpk;
            }
        }
    }
}

// ---------------------------------------------------------------------------
// K2: out = sqrt(clip(0.5*(cA+cB+A.B))). Verified round-1 split-K MFMA GEMM
// + fused epilogue (unchanged). 512 blocks, 4 waves/tile, XCD swizzle.
// ---------------------------------------------------------------------------
__global__ __launch_bounds__(256) void k_gemm(
    const unsigned short* __restrict__ featA,
    const unsigned short* __restrict__ featB,
    const float* __restrict__ cOut,
    float* __restrict__ out)
{
    __shared__ __attribute__((aligned(16))) float red[4][32][36];  // +4 pad

    const int t    = threadIdx.x;
    const int lane = t & 63;
    const int w    = t >> 6;          // wave id 0..3 = K-chunk id

    const int lin = blockIdx.x;
    const int swz = (lin & 7) * 64 + (lin >> 3);
    const int m0 = (swz & 15) * 32;
    const int n0 = ((swz >> 4) & 15) * 32;
    const int b  = swz >> 8;

    const int fr = lane & 15;
    const int fq = lane >> 4;
    const int kbase = w * 288 + fq * 8;

    const unsigned short* pA0 = featA + (size_t)(b * 512 + n0 + fr) * KF + kbase;
    const unsigned short* pA1 = pA0 + (size_t)16 * KF;
    const unsigned short* pB0 = featB + (size_t)(b * 512 + m0 + fr) * KF + kbase;
    const unsigned short* pB1 = pB0 + (size_t)16 * KF;

    v4f acc00 = {0,0,0,0}, acc01 = {0,0,0,0}, acc10 = {0,0,0,0}, acc11 = {0,0,0,0};

    uint4 bA0[4], bA1[4], bB0[4], bB1[4];
    #pragma unroll
    for (int s = 0; s < 4; ++s) {
        bA0[s] = *(const uint4*)(pA0 + s * 32);
        bA1[s] = *(const uint4*)(pA1 + s * 32);
        bB0[s] = *(const uint4*)(pB0 + s * 32);
        bB1[s] = *(const uint4*)(pB1 + s * 32);
    }

    #pragma unroll
    for (int s = 0; s < 9; ++s) {
        const int slot = s & 3;
        v8bf a0  = as_v8bf(bA0[slot]);
        v8bf a1  = as_v8bf(bA1[slot]);
        v8bf b0v = as_v8bf(bB0[slot]);
        v8bf b1v = as_v8bf(bB1[slot]);
        const int kn = s + 4;
        if (kn < 9) {
            bA0[slot] = *(const uint4*)(pA0 + kn * 32);
            bA1[slot] = *(const uint4*)(pA1 + kn * 32);
            bB0[slot] = *(const uint4*)(pB0 + kn * 32);
            bB1[slot] = *(const uint4*)(pB1 + kn * 32);
        }
        acc00 = __builtin_amdgcn_mfma_f32_16x16x32_bf16(a0, b0v, acc00, 0, 0, 0);
        acc01 = __builtin_amdgcn_mfma_f32_16x16x32_bf16(a0, b1v, acc01, 0, 0, 0);
        acc10 = __builtin_amdgcn_mfma_f32_16x16x32_bf16(a1, b0v, acc10, 0, 0, 0);
        acc11 = __builtin_amdgcn_mfma_f32_16x16x32_bf16(a1, b1v, acc11, 0, 0, 0);
    }

    #pragma unroll
    for (int v = 0; v < 4; ++v) {
        red[w][fq * 4 + v][fr]           = acc00[v];
        red[w][fq * 4 + v][fr + 16]      = acc01[v];
        red[w][16 + fq * 4 + v][fr]      = acc10[v];
        red[w][16 + fq * 4 + v][fr + 16] = acc11[v];
    }
    __syncthreads();

    const int n_l  = t >> 3;
    const int m_l0 = (t & 7) * 4;
    float4 s0 = *(const float4*)&red[0][n_l][m_l0];
    float4 s1 = *(const float4*)&red[1][n_l][m_l0];
    float4 s2 = *(const float4*)&red[2][n_l][m_l0];
    float4 s3 = *(const float4*)&red[3][n_l][m_l0];

    const int   n_g = n0 + n_l;
    const float cA  = cOut[b * 512 + n_g];
    const float4 cB = *(const float4*)&cOut[1024 + b * 512 + m0 + m_l0];

    float4 res;
    {
        float tot[4] = { s0.x + s1.x + s2.x + s3.x,
                         s0.y + s1.y + s2.y + s3.y,
                         s0.z + s1.z + s2.z + s3.z,
                         s0.w + s1.w + s2.w + s3.w };
        const float cb[4] = { cB.x, cB.y, cB.z, cB.w };
        float* rp = (float*)&res;
        #pragma unroll
        for (int e = 0; e < 4; ++e) {
            float dsq = 0.5f * (tot[e] + cA + cb[e]);
            dsq = fminf(fmaxf(dsq, 1e-6f), 1e6f);
            rp[e] = sqrtf(dsq);
        }
    }
    *(float4*)&out[((size_t)(b * 512 + n_g)) * 512 + m0 + m_l0] = res;
}

// ---------------------------------------------------------------------------
extern "C" void kernel_launch(void* const* d_in, const int* in_sizes, int n_in,
                              void* d_out, int out_size, void* d_ws, size_t ws_size,
                              hipStream_t stream)
{
    const float* Q  = (const float*)d_in[0];
    const float* K  = (const float*)d_in[1];
    const float* w1 = (const float*)d_in[2];
    const float* b1 = (const float*)d_in[3];
    const float* w2 = (const float*)d_in[4];
    const float* b2 = (const float*)d_in[5];
    float* out = (float*)d_out;

    unsigned short* featA = (unsigned short*)d_ws;            // [1024][1152] bf16
    unsigned short* featB = featA + (size_t)1024 * KF;        // [1024][1152] bf16
    float* cOut = (float*)(featB + (size_t)1024 * KF);        // [2048] fp32

    k_feat<<<dim3(512), dim3(256), 0, stream>>>(Q, K, w1, b1, w2, b2, featA, featB, cOut);
    k_gemm<<<dim3(512), dim3(256), 0, stream>>>(featA, featB, cOut, out);
}

// Round 13
// 99.621 us; speedup vs baseline: 1.1273x; 1.1273x over previous
//
#include <hip/hip_runtime.h>
#include <math.h>

namespace {
constexpr int KF  = 1152;   // padded feature dim (1120 used + 32 zeros)
constexpr int RPB = 2;      // rows per k_feat block (grid 1024, 4 blk/CU resident)
}

typedef __bf16 v8bf __attribute__((ext_vector_type(8)));
typedef float  v4f  __attribute__((ext_vector_type(4)));

__device__ __forceinline__ unsigned short f2bf(float f) {
    union { float f; unsigned u; } v; v.f = f;
    unsigned r = v.u + 0x7FFFu + ((v.u >> 16) & 1u);
    return (unsigned short)(r >> 16);
}

__device__ __forceinline__ v8bf as_v8bf(uint4 u) {
    union { uint4 u; v8bf b; } c; c.u = u; return c.b;
}

// ---------------------------------------------------------------------------
// K1: per-row feature builder — VERIFIED round-10 version (100.66us total),
// restored byte-for-byte after R11 (8 blk/CU: null-to-negative) and R12
// (barrier-free wave-per-row: 2x slower, lost cross-row w2 amortization)
// falsified the remaining structural theories.
//  (1) launch_bounds(256,4): VGPR<=128 -> 4 blocks/CU resident (saturation
//      point of the occupancy response curve: 2->4 gave 2.6x, 4->8 null)
//  (2) G-stage: fixed-trip 8x float4, fully unrolled (tril zeros -> exact)
//  (3) u-stage: rowoff LDS table replaces per-iter j*(65-j)/2 muls
//  (4) raw-stage: fully-upper quads (j0>i) skip the 512-FMA/64-load block
// ---------------------------------------------------------------------------
__global__ __launch_bounds__(256, 4) void k_feat(
    const float* __restrict__ Q, const float* __restrict__ K,
    const float* __restrict__ w1, const float* __restrict__ b1,
    const float* __restrict__ w2, const float* __restrict__ b2,
    unsigned short* __restrict__ featA, unsigned short* __restrict__ featB,
    float* __restrict__ cOut)
{
    __shared__ __attribute__((aligned(16))) float x_s[RPB][32];
    __shared__ __attribute__((aligned(16))) float h_s[RPB][64];
    __shared__ __attribute__((aligned(16))) float L_s[RPB][32][36];
    __shared__ __attribute__((aligned(16))) float G_s[RPB][528];   // col-major packed
    __shared__ __attribute__((aligned(16))) float u_s[RPB][32];
    __shared__ unsigned short tri_s[528];                          // (i<<8)|j
    __shared__ unsigned short rowoff_s[32];                        // j*(65-j)/2

    const int t  = threadIdx.x;
    const int g0 = blockIdx.x * RPB;

    // ---- triangular index + rowoff tables (once)
    for (int pr = t; pr < 528; pr += 256) {
        int j = (int)((65.0f - sqrtf(4225.0f - 8.0f * (float)pr)) * 0.5f);
        while (j > 0 && j * (65 - j) / 2 > pr) --j;
        while ((j + 1) * (64 - j) / 2 <= pr) ++j;
        int i = j + (pr - j * (65 - j) / 2);
        tri_s[pr] = (unsigned short)((i << 8) | j);
    }
    if (t < 32) rowoff_s[t] = (unsigned short)(t * (65 - t) / 2);

    // ---- load x
    if (t < RPB * 32) {
        int r = t >> 5, i = t & 31;
        int g = g0 + r;
        const float* src = (g < 1024) ? (Q + (size_t)g * 32)
                                      : (K + (size_t)(g - 1024) * 32);
        x_s[r][i] = src[i];
    }
    __syncthreads();

    // ---- h = silu(x @ w1 + b1): RPB*64 outputs, threads 0..127
    if (t < RPB * 64) {
        int r = t >> 6, j = t & 63;
        float z = b1[j];
        #pragma unroll
        for (int i = 0; i < 32; ++i) z = fmaf(x_s[r][i], w1[i * 64 + j], z);
        h_s[r][j] = z / (1.0f + __expf(-z));
    }
    __syncthreads();

    // ---- raw = h @ w2 + b2 -> L.  Thread t owns p-quad [4t,4t+4), all rows.
    // Fully-upper quads (j0 > i) skip the FMA/load block: outputs are val=0.
    {
        const int p4 = t * 4;
        const int i  = p4 >> 5;
        const int j0 = p4 & 31;
        float acc[RPB][4];
        float4 bq = *(const float4*)&b2[p4];
        #pragma unroll
        for (int r = 0; r < RPB; ++r) {
            acc[r][0] = bq.x; acc[r][1] = bq.y; acc[r][2] = bq.z; acc[r][3] = bq.w;
        }
        if (j0 <= i) {   // quad contains at least one lower/diag element
            for (int jb = 0; jb < 8; ++jb) {
                float h8[RPB][8];
                #pragma unroll
                for (int r = 0; r < RPB; ++r) {
                    *(float4*)&h8[r][0] = *(const float4*)&h_s[r][jb * 8 + 0];
                    *(float4*)&h8[r][4] = *(const float4*)&h_s[r][jb * 8 + 4];
                }
                #pragma unroll
                for (int jj = 0; jj < 8; ++jj) {
                    float4 w = *(const float4*)&w2[(size_t)(jb * 8 + jj) * 1024 + p4];
                    #pragma unroll
                    for (int r = 0; r < RPB; ++r) {
                        acc[r][0] = fmaf(h8[r][jj], w.x, acc[r][0]);
                        acc[r][1] = fmaf(h8[r][jj], w.y, acc[r][1]);
                        acc[r][2] = fmaf(h8[r][jj], w.z, acc[r][2]);
                        acc[r][3] = fmaf(h8[r][jj], w.w, acc[r][3]);
                    }
                }
            }
        }
        #pragma unroll
        for (int r = 0; r < RPB; ++r) {
            float4 lv;
            float* lvp = (float*)&lv;
            #pragma unroll
            for (int e = 0; e < 4; ++e) {
                int j = j0 + e;
                float raw = acc[r][e];
                float ex = __expf(0.4f * raw);
                float c5 = 5.0f * (ex - 1.0f) / (ex + 1.0f);   // 5*tanh(raw/5)
                float val;
                if (i < j)       val = 0.0f;
                else if (i == j) { float z = c5 + 1.0f; val = log1pf(__expf(z)) + 1e-4f; }
                else             val = c5;
                lvp[e] = val;
            }
            *(float4*)&L_s[r][i][j0] = lv;
        }
    }
    __syncthreads();

    // ---- G = L L^T: fixed-trip, fully unrolled (tril zeros make extra
    // products exact 0; association within the last partial group changes
    // by <=1ulp vs the old remainder loop)
    for (int idx = t; idx < RPB * 528; idx += 256) {
        int r  = idx / 528;
        int pr = idx - r * 528;
        int tv = tri_s[pr];
        int i = tv >> 8, j = tv & 255;
        const float* Li = &L_s[r][i][0];
        const float* Lj = &L_s[r][j][0];
        float s = 0.0f;
        #pragma unroll
        for (int q = 0; q < 8; ++q) {
            float4 a  = *(const float4*)&Li[q * 4];
            float4 bb = *(const float4*)&Lj[q * 4];
            s += a.x * bb.x + a.y * bb.y + a.z * bb.z + a.w * bb.w;
        }
        G_s[r][pr] = s;
    }
    __syncthreads();

    // ---- u = G x (rowoff table; threads 0..63)
    if (t < RPB * 32) {
        int r = t >> 5, i = t & 31;
        const int base_i = (int)rowoff_s[i] - i;
        float s = 0.0f;
        #pragma unroll
        for (int j = 0; j < 32; ++j) {
            int gidx = (j <= i) ? ((int)rowoff_s[j] + i - j) : (base_i + j);
            s = fmaf(G_s[r][gidx], x_s[r][j], s);
        }
        u_s[r][i] = s;
    }
    __syncthreads();

    // ---- c = u . x
    if (t < RPB) {
        float s = 0.0f;
        #pragma unroll
        for (int i = 0; i < 32; ++i) s = fmaf(u_s[t][i], x_s[t][i], s);
        cOut[g0 + t] = s;
    }

    // ---- feature write: quads of 4 bf16, packed uint2 stores (coalesced).
    for (int idx = t; idx < RPB * (KF / 4); idx += 256) {
        int r   = idx / (KF / 4);
        int q   = idx - r * (KF / 4);
        int pos = q * 4;
        int g   = g0 + r;
        bool isA = (g < 1024);
        unsigned short* dst = isA ? (featA + (size_t)g * KF)
                                  : (featB + (size_t)(g - 1024) * KF);
        unsigned short ev[4];
        #pragma unroll
        for (int e = 0; e < 4; ++e) {
            int p = pos + e;
            float va;
            if (p < 1056) {
                int pr = (p < 528) ? p : p - 528;
                bool wantG = (p < 528) ? isA : !isA;
                int tv = tri_s[pr];
                int i = tv >> 8, j = tv & 255;
                float gv = G_s[r][pr] * ((i == j) ? 1.0f : 2.0f);
                float ov = x_s[r][i] * x_s[r][j];
                va = wantG ? gv : ov;
            } else if (p < 1088) {
                int i = p - 1056;
                va = isA ? u_s[r][i] : -2.0f * x_s[r][i];
            } else if (p < 1120) {
                int i = p - 1088;
                va = isA ? x_s[r][i] : -2.0f * u_s[r][i];
            } else {
                va = 0.0f;   // ws re-poisoned 0xAA — pad must be written
            }
            ev[e] = f2bf(va);
        }
        uint2 w;
        w.x = (unsigned)ev[0] | ((unsigned)ev[1] << 16);
        w.y = (unsigned)ev[2] | ((unsigned)ev[3] << 16);
        *(uint2*)(dst + pos) = w;
    }
}

// ---------------------------------------------------------------------------
// K2: out = sqrt(clip(0.5*(cA+cB+A.B))). Verified round-1 split-K MFMA GEMM
// + fused epilogue (unchanged). 512 blocks, 4 waves/tile, XCD swizzle.
// ---------------------------------------------------------------------------
__global__ __launch_bounds__(256) void k_gemm(
    const unsigned short* __restrict__ featA,
    const unsigned short* __restrict__ featB,
    const float* __restrict__ cOut,
    float* __restrict__ out)
{
    __shared__ __attribute__((aligned(16))) float red[4][32][36];  // +4 pad

    const int t    = threadIdx.x;
    const int lane = t & 63;
    const int w    = t >> 6;          // wave id 0..3 = K-chunk id

    const int lin = blockIdx.x;
    const int swz = (lin & 7) * 64 + (lin >> 3);
    const int m0 = (swz & 15) * 32;
    const int n0 = ((swz >> 4) & 15) * 32;
    const int b  = swz >> 8;

    const int fr = lane & 15;
    const int fq = lane >> 4;
    const int kbase = w * 288 + fq * 8;

    const unsigned short* pA0 = featA + (size_t)(b * 512 + n0 + fr) * KF + kbase;
    const unsigned short* pA1 = pA0 + (size_t)16 * KF;
    const unsigned short* pB0 = featB + (size_t)(b * 512 + m0 + fr) * KF + kbase;
    const unsigned short* pB1 = pB0 + (size_t)16 * KF;

    v4f acc00 = {0,0,0,0}, acc01 = {0,0,0,0}, acc10 = {0,0,0,0}, acc11 = {0,0,0,0};

    uint4 bA0[4], bA1[4], bB0[4], bB1[4];
    #pragma unroll
    for (int s = 0; s < 4; ++s) {
        bA0[s] = *(const uint4*)(pA0 + s * 32);
        bA1[s] = *(const uint4*)(pA1 + s * 32);
        bB0[s] = *(const uint4*)(pB0 + s * 32);
        bB1[s] = *(const uint4*)(pB1 + s * 32);
    }

    #pragma unroll
    for (int s = 0; s < 9; ++s) {
        const int slot = s & 3;
        v8bf a0  = as_v8bf(bA0[slot]);
        v8bf a1  = as_v8bf(bA1[slot]);
        v8bf b0v = as_v8bf(bB0[slot]);
        v8bf b1v = as_v8bf(bB1[slot]);
        const int kn = s + 4;
        if (kn < 9) {
            bA0[slot] = *(const uint4*)(pA0 + kn * 32);
            bA1[slot] = *(const uint4*)(pA1 + kn * 32);
            bB0[slot] = *(const uint4*)(pB0 + kn * 32);
            bB1[slot] = *(const uint4*)(pB1 + kn * 32);
        }
        acc00 = __builtin_amdgcn_mfma_f32_16x16x32_bf16(a0, b0v, acc00, 0, 0, 0);
        acc01 = __builtin_amdgcn_mfma_f32_16x16x32_bf16(a0, b1v, acc01, 0, 0, 0);
        acc10 = __builtin_amdgcn_mfma_f32_16x16x32_bf16(a1, b0v, acc10, 0, 0, 0);
        acc11 = __builtin_amdgcn_mfma_f32_16x16x32_bf16(a1, b1v, acc11, 0, 0, 0);
    }

    #pragma unroll
    for (int v = 0; v < 4; ++v) {
        red[w][fq * 4 + v][fr]           = acc00[v];
        red[w][fq * 4 + v][fr + 16]      = acc01[v];
        red[w][16 + fq * 4 + v][fr]      = acc10[v];
        red[w][16 + fq * 4 + v][fr + 16] = acc11[v];
    }
    __syncthreads();

    const int n_l  = t >> 3;
    const int m_l0 = (t & 7) * 4;
    float4 s0 = *(const float4*)&red[0][n_l][m_l0];
    float4 s1 = *(const float4*)&red[1][n_l][m_l0];
    float4 s2 = *(const float4*)&red[2][n_l][m_l0];
    float4 s3 = *(const float4*)&red[3][n_l][m_l0];

    const int   n_g = n0 + n_l;
    const float cA  = cOut[b * 512 + n_g];
    const float4 cB = *(const float4*)&cOut[1024 + b * 512 + m0 + m_l0];

    float4 res;
    {
        float tot[4] = { s0.x + s1.x + s2.x + s3.x,
                         s0.y + s1.y + s2.y + s3.y,
                         s0.z + s1.z + s2.z + s3.z,
                         s0.w + s1.w + s2.w + s3.w };
        const float cb[4] = { cB.x, cB.y, cB.z, cB.w };
        float* rp = (float*)&res;
        #pragma unroll
        for (int e = 0; e < 4; ++e) {
            float dsq = 0.5f * (tot[e] + cA + cb[e]);
            dsq = fminf(fmaxf(dsq, 1e-6f), 1e6f);
            rp[e] = sqrtf(dsq);
        }
    }
    *(float4*)&out[((size_t)(b * 512 + n_g)) * 512 + m0 + m_l0] = res;
}

// ---------------------------------------------------------------------------
extern "C" void kernel_launch(void* const* d_in, const int* in_sizes, int n_in,
                              void* d_out, int out_size, void* d_ws, size_t ws_size,
                              hipStream_t stream)
{
    const float* Q  = (const float*)d_in[0];
    const float* K  = (const float*)d_in[1];
    const float* w1 = (const float*)d_in[2];
    const float* b1 = (const float*)d_in[3];
    const float* w2 = (const float*)d_in[4];
    const float* b2 = (const float*)d_in[5];
    float* out = (float*)d_out;

    unsigned short* featA = (unsigned short*)d_ws;            // [1024][1152] bf16
    unsigned short* featB = featA + (size_t)1024 * KF;        // [1024][1152] bf16
    float* cOut = (float*)(featB + (size_t)1024 * KF);        // [2048] fp32

    k_feat<<<dim3(2048 / RPB), dim3(256), 0, stream>>>(Q, K, w1, b1, w2, b2, featA, featB, cOut);
    k_gemm<<<dim3(512), dim3(256), 0, stream>>>(featA, featB, cOut, out);
}